// Round 7
// baseline (80.815 us; speedup 1.0000x reference)
//
#include <hip/hip_runtime.h>
#include <hip/hip_bf16.h>

#define EPS 1e-5f

typedef _Float16 f16x8 __attribute__((ext_vector_type(8)));
typedef short short4v __attribute__((ext_vector_type(4)));
typedef float f32x4 __attribute__((ext_vector_type(4)));

static __device__ __forceinline__ unsigned short f2h(float x) {
    _Float16 h = (_Float16)x;
    return *reinterpret_cast<unsigned short*>(&h);
}

// ------- Kernel 1: 1x1 convs (+BN fold for K): K (B,Nv,64) fp16, V^T (B,64,Nv) fp16 -------
__global__ void conv_kv_kernel(const float* __restrict__ v,
                               const float* __restrict__ k_w, const float* __restrict__ v_w,
                               const float* __restrict__ kg, const float* __restrict__ kbe,
                               const float* __restrict__ km, const float* __restrict__ kvv,
                               unsigned short* __restrict__ Kt, unsigned short* __restrict__ Vt) {
    __shared__ float kw_lds[128 * 64];  // [c][o], XOR swizzled (write-side conflict fix)
    __shared__ float vw_lds[128 * 64];
    const int t = threadIdx.x;
    const int b = blockIdx.y;
#pragma unroll
    for (int r = 0; r < 32; ++r) {
        int idx = r * 256 + t;                   // c fast -> coalesced global reads
        int o = idx >> 7, c = idx & 127;
        int sw = c * 64 + (o ^ (c & 31));
        kw_lds[sw] = k_w[idx];                   // raw; BN scale applied post-sum
        vw_lds[sw] = v_w[idx];
    }
    const int o = t & 63, g = t >> 6;
    const int m0 = blockIdx.x * 16 + g * 4;
    const float invk = kg[o] * rsqrtf(kvv[o] + EPS);
    const float biask = kbe[o] - km[o] * invk;
    __syncthreads();
    float acck[4] = {0.f, 0.f, 0.f, 0.f};
    float accv[4] = {0.f, 0.f, 0.f, 0.f};
    const float* vbase = v + (size_t)b * 128 * 1024 + m0;
    float4 vnext = *reinterpret_cast<const float4*>(vbase);
    for (int c = 0; c < 128; ++c) {
        float4 v0 = vnext;
        vnext = *reinterpret_cast<const float4*>(vbase + (size_t)((c + 1) & 127) * 1024);
        float kw = kw_lds[c * 64 + (o ^ (c & 31))];
        float vw = vw_lds[c * 64 + (o ^ (c & 31))];
        acck[0] += kw * v0.x; acck[1] += kw * v0.y; acck[2] += kw * v0.z; acck[3] += kw * v0.w;
        accv[0] += vw * v0.x; accv[1] += vw * v0.y; accv[2] += vw * v0.z; accv[3] += vw * v0.w;
    }
#pragma unroll
    for (int j = 0; j < 4; ++j)
        Kt[(size_t)(b * 1024 + m0 + j) * 64 + o] = f2h(acck[j] * invk + biask);
    unsigned short vb[4];
#pragma unroll
    for (int j = 0; j < 4; ++j) vb[j] = f2h(accv[j]);
    *reinterpret_cast<short4v*>(&Vt[(size_t)(b * 64 + o) * 1024 + m0]) =
        *reinterpret_cast<const short4v*>(vb);
}

// ------- Kernel 2: fused BN(q) + flash attention; K/V read direct from L2 (no staging) -------
struct Frags { f16x8 k[4][2]; f16x8 v[4][2]; };

static __device__ __forceinline__ void load_frags(Frags& F,
        const unsigned short* __restrict__ Kb, const unsigned short* __restrict__ Vb, int kt) {
#pragma unroll
    for (int kb = 0; kb < 4; ++kb)
#pragma unroll
        for (int h = 0; h < 2; ++h)
            F.k[kb][h] = *reinterpret_cast<const f16x8*>(Kb + kt * 4096 + kb * 1024 + h * 32);
#pragma unroll
    for (int cb = 0; cb < 4; ++cb)
#pragma unroll
        for (int h = 0; h < 2; ++h)
            F.v[cb][h] = *reinterpret_cast<const f16x8*>(Vb + cb * 16384 + kt * 64 + h * 32);
}

static __device__ __forceinline__ void attn_body(const Frags& F,
        const f16x8& qf0, const f16x8& qf1, unsigned short* __restrict__ pTw,
        int qr, int g, f32x4 (&oacc)[4], float& m_run, float& lpart) {
    // S^T[key][qrow] = K · Q^T (pre-scaled by log2e via BN fold)
    f32x4 s[4];
#pragma unroll
    for (int kb = 0; kb < 4; ++kb) {
        f32x4 acc = {0.f, 0.f, 0.f, 0.f};
        acc = __builtin_amdgcn_mfma_f32_16x16x32_f16(F.k[kb][0], qf0, acc, 0, 0, 0);
        s[kb] = __builtin_amdgcn_mfma_f32_16x16x32_f16(F.k[kb][1], qf1, acc, 0, 0, 0);
    }
    // per-lane max (tree); cross-lane reduce only when the defer threshold trips
    float a0 = fmaxf(fmaxf(s[0][0], s[0][1]), fmaxf(s[0][2], s[0][3]));
    float a1 = fmaxf(fmaxf(s[1][0], s[1][1]), fmaxf(s[1][2], s[1][3]));
    float a2 = fmaxf(fmaxf(s[2][0], s[2][1]), fmaxf(s[2][2], s[2][3]));
    float a3 = fmaxf(fmaxf(s[3][0], s[3][1]), fmaxf(s[3][2], s[3][3]));
    float lmax = fmaxf(fmaxf(a0, a1), fmaxf(a2, a3));
    if (!__all(lmax - m_run <= 11.0f)) {
        float tmax = fmaxf(lmax, __shfl_xor(lmax, 16));
        tmax = fmaxf(tmax, __shfl_xor(tmax, 32));
        float mnew = fmaxf(m_run, tmax);
        float sc = exp2f(m_run - mnew);
        lpart *= sc;
#pragma unroll
        for (int cb = 0; cb < 4; ++cb) oacc[cb] *= sc;
        m_run = mnew;
    }
    float ps0 = 0.f, ps1 = 0.f;
#pragma unroll
    for (int kb = 0; kb < 4; ++kb) {
        float p0 = exp2f(s[kb][0] - m_run), p1 = exp2f(s[kb][1] - m_run);
        float p2 = exp2f(s[kb][2] - m_run), p3 = exp2f(s[kb][3] - m_run);
        ps0 += p0 + p2; ps1 += p1 + p3;
        uint2 wv;
        wv.x = __builtin_bit_cast(unsigned int, __builtin_amdgcn_cvt_pkrtz(p0, p1));
        wv.y = __builtin_bit_cast(unsigned int, __builtin_amdgcn_cvt_pkrtz(p2, p3));
        *reinterpret_cast<uint2*>(pTw + qr * 80 + kb * 16 + g * 4) = wv;
    }
    lpart += ps0 + ps1;
    // O^T += V^T · P^T   (pT is per-wave; wave-internal LDS dependency only)
#pragma unroll
    for (int ch = 0; ch < 2; ++ch) {
        f16x8 pf = *reinterpret_cast<const f16x8*>(pTw + qr * 80 + ch * 32 + g * 8);
#pragma unroll
        for (int cb = 0; cb < 4; ++cb)
            oacc[cb] = __builtin_amdgcn_mfma_f32_16x16x32_f16(F.v[cb][ch], pf, oacc[cb], 0, 0, 0);
    }
}

__global__ __launch_bounds__(256, 2) void attn_kernel(const float* __restrict__ q,
        const float* __restrict__ qg, const float* __restrict__ qb,
        const float* __restrict__ qm, const float* __restrict__ qv,
        const unsigned short* __restrict__ Kt, const unsigned short* __restrict__ Vt,
        float* __restrict__ out) {
    __shared__ unsigned short pT[4][16 * 80];    // per-wave [qrow][key], stride 80 shorts
    __shared__ float ib[128];                    // inv*log2e [64], bias*log2e [64]
    const int t = threadIdx.x;
    const int w = t >> 6, lane = t & 63, g = lane >> 4, qr = lane & 15;
    const int b = blockIdx.y, n0 = blockIdx.x * 64;
    const int nq = n0 + w * 16 + qr;

    const unsigned short* Kb = Kt + (size_t)(b * 1024 + qr) * 64 + g * 8;
    const unsigned short* Vb = Vt + (size_t)(b * 64 + qr) * 1024 + g * 8;

    Frags FA, FB;
    load_frags(FA, Kb, Vb, 0);                   // in flight under BN/Q setup

    if (t < 64) {
        float inv = qg[t] * rsqrtf(qv[t] + EPS);
        ib[t] = inv * 1.44269504f;               // softmax in base-2
        ib[64 + t] = (qb[t] - qm[t] * inv) * 1.44269504f;
    }
    __syncthreads();

    f16x8 qf0, qf1;
#pragma unroll
    for (int j = 0; j < 8; ++j) {
        int c0 = g * 8 + j, c1 = 32 + g * 8 + j;
        float x0 = q[(size_t)(b * 64 + c0) * 4096 + nq];
        float x1 = q[(size_t)(b * 64 + c1) * 4096 + nq];
        qf0[j] = (_Float16)(x0 * ib[c0] + ib[64 + c0]);
        qf1[j] = (_Float16)(x1 * ib[c1] + ib[64 + c1]);
    }

    f32x4 oacc[4];
#pragma unroll
    for (int cb = 0; cb < 4; ++cb) oacc[cb] = (f32x4){0.f, 0.f, 0.f, 0.f};
    float m_run = -1e30f, lpart = 0.f;
    unsigned short* pTw = pT[w];

#pragma unroll 1
    for (int kt = 0; kt < 16; kt += 2) {
        load_frags(FB, Kb, Vb, kt + 1);
        attn_body(FA, qf0, qf1, pTw, qr, g, oacc, m_run, lpart);
        if (kt < 14) load_frags(FA, Kb, Vb, kt + 2);
        attn_body(FB, qf0, qf1, pTw, qr, g, oacc, m_run, lpart);
    }

    float l = lpart + __shfl_xor(lpart, 16);
    l += __shfl_xor(l, 32);
    const float rl = 1.f / l;
#pragma unroll
    for (int cb = 0; cb < 4; ++cb)
#pragma unroll
        for (int i = 0; i < 4; ++i)
            out[(size_t)(b * 64 + cb * 16 + g * 4 + i) * 4096 + n0 + w * 16 + qr] = oacc[cb][i] * rl;
}

extern "C" void kernel_launch(void* const* d_in, const int* in_sizes, int n_in,
                              void* d_out, int out_size, void* d_ws, size_t ws_size,
                              hipStream_t stream) {
    const float* q   = (const float*)d_in[0];
    const float* v   = (const float*)d_in[1];
    const float* k_w = (const float*)d_in[2];
    const float* v_w = (const float*)d_in[3];
    const float* qg  = (const float*)d_in[4];
    const float* qb  = (const float*)d_in[5];
    const float* qm  = (const float*)d_in[6];
    const float* qv  = (const float*)d_in[7];
    const float* kg  = (const float*)d_in[8];
    const float* kbe = (const float*)d_in[9];
    const float* km  = (const float*)d_in[10];
    const float* kvv = (const float*)d_in[11];

    unsigned short* Kt = (unsigned short*)d_ws;            // 8*1024*64 fp16 = 1 MB
    unsigned short* Vt = Kt + (size_t)8 * 1024 * 64;       // 1 MB

    conv_kv_kernel<<<dim3(64, 8), 256, 0, stream>>>(v, k_w, v_w, kg, kbe, km, kvv, Kt, Vt);
    attn_kernel<<<dim3(64, 8), 256, 0, stream>>>(q, qg, qb, qm, qv, Kt, Vt, (float*)d_out);
}

// Round 8
// 51.118 us; speedup vs baseline: 1.5809x; 1.5809x over previous
//
#include <hip/hip_runtime.h>
#include <hip/hip_bf16.h>

#define EPS 1e-5f

typedef _Float16 f16x8 __attribute__((ext_vector_type(8)));
typedef short short4v __attribute__((ext_vector_type(4)));
typedef short short8v __attribute__((ext_vector_type(8)));
typedef float f32x4 __attribute__((ext_vector_type(4)));

static __device__ __forceinline__ unsigned short f2h(float x) {
    _Float16 h = (_Float16)x;
    return *reinterpret_cast<unsigned short*>(&h);
}

// ------- Kernel 1: 1x1 convs (+BN fold for K): K (B,Nv,64) fp16, V^T (B,64,Nv) fp16 -------
// 8-deep ping-pong prefetch of the (wave-uniform) v float4 -> L2 latency hidden.
__global__ void conv_kv_kernel(const float* __restrict__ v,
                               const float* __restrict__ k_w, const float* __restrict__ v_w,
                               const float* __restrict__ kg, const float* __restrict__ kbe,
                               const float* __restrict__ km, const float* __restrict__ kvv,
                               unsigned short* __restrict__ Kt, unsigned short* __restrict__ Vt) {
    __shared__ float kw_lds[128 * 64];  // [c][o], XOR swizzled
    __shared__ float vw_lds[128 * 64];
    const int t = threadIdx.x;
    const int b = blockIdx.y;
#pragma unroll
    for (int r = 0; r < 32; ++r) {
        int idx = r * 256 + t;
        int o = idx >> 7, c = idx & 127;
        int sw = c * 64 + (o ^ (c & 31));
        kw_lds[sw] = k_w[idx];
        vw_lds[sw] = v_w[idx];
    }
    const int o = t & 63, g = t >> 6;
    const int m0 = blockIdx.x * 16 + g * 4;
    const float invk = kg[o] * rsqrtf(kvv[o] + EPS);
    const float biask = kbe[o] - km[o] * invk;
    __syncthreads();
    float acck[4] = {0.f, 0.f, 0.f, 0.f};
    float accv[4] = {0.f, 0.f, 0.f, 0.f};
    const float* vbase = v + (size_t)b * 128 * 1024 + m0;
    float4 vA[8], vB[8];
#pragma unroll
    for (int j = 0; j < 8; ++j) vA[j] = *reinterpret_cast<const float4*>(vbase + (size_t)j * 1024);
#pragma unroll 1
    for (int cb = 0; cb < 128; cb += 16) {
#pragma unroll
        for (int j = 0; j < 8; ++j)
            vB[j] = *reinterpret_cast<const float4*>(vbase + (size_t)(cb + 8 + j) * 1024);
#pragma unroll
        for (int j = 0; j < 8; ++j) {
            int c = cb + j;
            float kw = kw_lds[c * 64 + (o ^ (c & 31))];
            float vw = vw_lds[c * 64 + (o ^ (c & 31))];
            float4 v0 = vA[j];
            acck[0] += kw * v0.x; acck[1] += kw * v0.y; acck[2] += kw * v0.z; acck[3] += kw * v0.w;
            accv[0] += vw * v0.x; accv[1] += vw * v0.y; accv[2] += vw * v0.z; accv[3] += vw * v0.w;
        }
#pragma unroll
        for (int j = 0; j < 8; ++j)
            vA[j] = *reinterpret_cast<const float4*>(vbase + (size_t)((cb + 16 + j) & 127) * 1024);
#pragma unroll
        for (int j = 0; j < 8; ++j) {
            int c = cb + 8 + j;
            float kw = kw_lds[c * 64 + (o ^ (c & 31))];
            float vw = vw_lds[c * 64 + (o ^ (c & 31))];
            float4 v0 = vB[j];
            acck[0] += kw * v0.x; acck[1] += kw * v0.y; acck[2] += kw * v0.z; acck[3] += kw * v0.w;
            accv[0] += vw * v0.x; accv[1] += vw * v0.y; accv[2] += vw * v0.z; accv[3] += vw * v0.w;
        }
    }
#pragma unroll
    for (int j = 0; j < 4; ++j)
        Kt[(size_t)(b * 1024 + m0 + j) * 64 + o] = f2h(acck[j] * invk + biask);
    unsigned short vb[4];
#pragma unroll
    for (int j = 0; j < 4; ++j) vb[j] = f2h(accv[j]);
    *reinterpret_cast<short4v*>(&Vt[(size_t)(b * 64 + o) * 1024 + m0]) =
        *reinterpret_cast<const short4v*>(vb);
}

// ------- Kernel 2: fused BN(q) + flash attention, LDS-staged dbuf, KV split 2-way -------
__global__ __launch_bounds__(256, 3) void attn_kernel(const float* __restrict__ q,
        const float* __restrict__ qg, const float* __restrict__ qb,
        const float* __restrict__ qm, const float* __restrict__ qv,
        const unsigned short* __restrict__ Kt, const unsigned short* __restrict__ Vt,
        float* __restrict__ Opart, float* __restrict__ Mpart, float* __restrict__ Lpart) {
    __shared__ unsigned short kT[2][64 * 72];    // [key][c], stride 72 (2-way = free)
    __shared__ unsigned short vT[2][64 * 72];    // [c][key]
    __shared__ unsigned short pT[4][16 * 72];    // per-wave [qrow][key]
    __shared__ float ib[128];                    // inv*log2e, bias*log2e
    const int t = threadIdx.x;
    const int w = t >> 6, lane = t & 63, g = lane >> 4, qr = lane & 15;
    const int b = blockIdx.y, n0 = blockIdx.x * 64, s = blockIdx.z;
    const int nq = n0 + w * 16 + qr;
    const int kt0 = s * 8;
    const int r0 = t >> 3, r1 = 32 + (t >> 3), o0 = (t & 7) * 8;

    // prologue: stage tile kt0 (loads in flight under BN/Q setup)
    short8v ka0 = *reinterpret_cast<const short8v*>(Kt + (size_t)(b * 1024 + kt0 * 64 + r0) * 64 + o0);
    short8v ka1 = *reinterpret_cast<const short8v*>(Kt + (size_t)(b * 1024 + kt0 * 64 + r1) * 64 + o0);
    short8v va0 = *reinterpret_cast<const short8v*>(Vt + (size_t)(b * 64 + r0) * 1024 + kt0 * 64 + o0);
    short8v va1 = *reinterpret_cast<const short8v*>(Vt + (size_t)(b * 64 + r1) * 1024 + kt0 * 64 + o0);

    if (t < 64) {
        float inv = qg[t] * rsqrtf(qv[t] + EPS);
        ib[t] = inv * 1.44269504f;               // softmax in base-2
        ib[64 + t] = (qb[t] - qm[t] * inv) * 1.44269504f;
    }
    __syncthreads();

    f16x8 qf0, qf1;
#pragma unroll
    for (int j = 0; j < 8; ++j) {
        int c0 = g * 8 + j, c1 = 32 + g * 8 + j;
        float x0 = q[(size_t)(b * 64 + c0) * 4096 + nq];
        float x1 = q[(size_t)(b * 64 + c1) * 4096 + nq];
        qf0[j] = (_Float16)(x0 * ib[c0] + ib[64 + c0]);
        qf1[j] = (_Float16)(x1 * ib[c1] + ib[64 + c1]);
    }

    *reinterpret_cast<short8v*>(&kT[0][r0 * 72 + o0]) = ka0;
    *reinterpret_cast<short8v*>(&kT[0][r1 * 72 + o0]) = ka1;
    *reinterpret_cast<short8v*>(&vT[0][r0 * 72 + o0]) = va0;
    *reinterpret_cast<short8v*>(&vT[0][r1 * 72 + o0]) = va1;

    f32x4 oacc[4];
#pragma unroll
    for (int cb = 0; cb < 4; ++cb) oacc[cb] = (f32x4){0.f, 0.f, 0.f, 0.f};
    float m_run = -1e30f, lpart = 0.f;
    unsigned short* pTw = pT[w];
    int cur = 0;

#pragma unroll 1
    for (int i = 0; i < 8; ++i) {
        __syncthreads();                          // buf[cur] staged by all waves
        short8v kn0, kn1, vn0, vn1;
        if (i < 7) {                              // T14: issue next tile's loads now
            const unsigned short* Kp = Kt + (size_t)(b * 1024 + (kt0 + i + 1) * 64) * 64;
            const unsigned short* Vp = Vt + (size_t)(b * 64) * 1024 + (kt0 + i + 1) * 64;
            kn0 = *reinterpret_cast<const short8v*>(Kp + r0 * 64 + o0);
            kn1 = *reinterpret_cast<const short8v*>(Kp + r1 * 64 + o0);
            vn0 = *reinterpret_cast<const short8v*>(Vp + r0 * 1024 + o0);
            vn1 = *reinterpret_cast<const short8v*>(Vp + r1 * 1024 + o0);
        }
        const unsigned short* kTile = kT[cur];
        const unsigned short* vTile = vT[cur];

        // S^T[key][qrow] = K · Q^T (pre-scaled by log2e via BN fold)
        f32x4 s4[4];
#pragma unroll
        for (int kb = 0; kb < 4; ++kb) {
            f16x8 kf0 = *reinterpret_cast<const f16x8*>(kTile + (kb * 16 + qr) * 72 + g * 8);
            f16x8 kf1 = *reinterpret_cast<const f16x8*>(kTile + (kb * 16 + qr) * 72 + 32 + g * 8);
            f32x4 acc = {0.f, 0.f, 0.f, 0.f};
            acc = __builtin_amdgcn_mfma_f32_16x16x32_f16(kf0, qf0, acc, 0, 0, 0);
            s4[kb] = __builtin_amdgcn_mfma_f32_16x16x32_f16(kf1, qf1, acc, 0, 0, 0);
        }
        // per-lane tree max; cross-lane reduce only when defer threshold trips
        float a0 = fmaxf(fmaxf(s4[0][0], s4[0][1]), fmaxf(s4[0][2], s4[0][3]));
        float a1 = fmaxf(fmaxf(s4[1][0], s4[1][1]), fmaxf(s4[1][2], s4[1][3]));
        float a2 = fmaxf(fmaxf(s4[2][0], s4[2][1]), fmaxf(s4[2][2], s4[2][3]));
        float a3 = fmaxf(fmaxf(s4[3][0], s4[3][1]), fmaxf(s4[3][2], s4[3][3]));
        float lmax = fmaxf(fmaxf(a0, a1), fmaxf(a2, a3));
        if (!__all(lmax - m_run <= 11.0f)) {
            float tmax = fmaxf(lmax, __shfl_xor(lmax, 16));
            tmax = fmaxf(tmax, __shfl_xor(tmax, 32));
            float mnew = fmaxf(m_run, tmax);
            float sc = exp2f(m_run - mnew);
            lpart *= sc;
#pragma unroll
            for (int cb = 0; cb < 4; ++cb) oacc[cb] *= sc;
            m_run = mnew;
        }
        float ps0 = 0.f, ps1 = 0.f;
#pragma unroll
        for (int kb = 0; kb < 4; ++kb) {
            float p0 = exp2f(s4[kb][0] - m_run), p1 = exp2f(s4[kb][1] - m_run);
            float p2 = exp2f(s4[kb][2] - m_run), p3 = exp2f(s4[kb][3] - m_run);
            ps0 += p0 + p2; ps1 += p1 + p3;
            uint2 wv;
            wv.x = __builtin_bit_cast(unsigned int, __builtin_amdgcn_cvt_pkrtz(p0, p1));
            wv.y = __builtin_bit_cast(unsigned int, __builtin_amdgcn_cvt_pkrtz(p2, p3));
            *reinterpret_cast<uint2*>(pTw + qr * 72 + kb * 16 + g * 4) = wv;
        }
        lpart += ps0 + ps1;
        // O^T += V^T · P^T (pT per-wave: wave-internal dependency only)
#pragma unroll
        for (int ch = 0; ch < 2; ++ch) {
            f16x8 pf = *reinterpret_cast<const f16x8*>(pTw + qr * 72 + ch * 32 + g * 8);
#pragma unroll
            for (int cb = 0; cb < 4; ++cb) {
                f16x8 vf = *reinterpret_cast<const f16x8*>(vTile + (cb * 16 + qr) * 72 + ch * 32 + g * 8);
                oacc[cb] = __builtin_amdgcn_mfma_f32_16x16x32_f16(vf, pf, oacc[cb], 0, 0, 0);
            }
        }
        __syncthreads();                          // all waves done reading buf[cur^1]
        if (i < 7) {
            *reinterpret_cast<short8v*>(&kT[cur ^ 1][r0 * 72 + o0]) = kn0;
            *reinterpret_cast<short8v*>(&kT[cur ^ 1][r1 * 72 + o0]) = kn1;
            *reinterpret_cast<short8v*>(&vT[cur ^ 1][r0 * 72 + o0]) = vn0;
            *reinterpret_cast<short8v*>(&vT[cur ^ 1][r1 * 72 + o0]) = vn1;
        }
        cur ^= 1;
    }

    float l = lpart + __shfl_xor(lpart, 16);
    l += __shfl_xor(l, 32);
    // unnormalized partials: O, plus per-row m, l for the merge
#pragma unroll
    for (int cb = 0; cb < 4; ++cb)
#pragma unroll
        for (int i = 0; i < 4; ++i)
            Opart[(size_t)((s * 8 + b) * 64 + cb * 16 + g * 4 + i) * 4096 + nq] = oacc[cb][i];
    if (g == 0) {
        Mpart[(s * 8 + b) * 4096 + nq] = m_run;
        Lpart[(s * 8 + b) * 4096 + nq] = l;
    }
}

// ------- Kernel 3: merge the two KV-split partials (base-2 LSE merge) -------
__global__ void merge_kernel(const float* __restrict__ Opart,
                             const float* __restrict__ Mpart, const float* __restrict__ Lpart,
                             float* __restrict__ out) {
    const int i = blockIdx.x * 256 + threadIdx.x;     // over 8*64*1024 float4s
    const int n = (i & 1023) * 4;
    const int c = (i >> 10) & 63;
    const int b = i >> 16;
    float4 m1 = *reinterpret_cast<const float4*>(&Mpart[b * 4096 + n]);
    float4 m2 = *reinterpret_cast<const float4*>(&Mpart[(8 + b) * 4096 + n]);
    float4 l1 = *reinterpret_cast<const float4*>(&Lpart[b * 4096 + n]);
    float4 l2 = *reinterpret_cast<const float4*>(&Lpart[(8 + b) * 4096 + n]);
    float4 O1 = *reinterpret_cast<const float4*>(&Opart[(size_t)(b * 64 + c) * 4096 + n]);
    float4 O2 = *reinterpret_cast<const float4*>(&Opart[(size_t)((8 + b) * 64 + c) * 4096 + n]);
    float4 r;
    {
        float M = fmaxf(m1.x, m2.x), w1 = exp2f(m1.x - M), w2 = exp2f(m2.x - M);
        r.x = (O1.x * w1 + O2.x * w2) / (l1.x * w1 + l2.x * w2);
    }
    {
        float M = fmaxf(m1.y, m2.y), w1 = exp2f(m1.y - M), w2 = exp2f(m2.y - M);
        r.y = (O1.y * w1 + O2.y * w2) / (l1.y * w1 + l2.y * w2);
    }
    {
        float M = fmaxf(m1.z, m2.z), w1 = exp2f(m1.z - M), w2 = exp2f(m2.z - M);
        r.z = (O1.z * w1 + O2.z * w2) / (l1.z * w1 + l2.z * w2);
    }
    {
        float M = fmaxf(m1.w, m2.w), w1 = exp2f(m1.w - M), w2 = exp2f(m2.w - M);
        r.w = (O1.w * w1 + O2.w * w2) / (l1.w * w1 + l2.w * w2);
    }
    *reinterpret_cast<float4*>(&out[(size_t)(b * 64 + c) * 4096 + n]) = r;
}

extern "C" void kernel_launch(void* const* d_in, const int* in_sizes, int n_in,
                              void* d_out, int out_size, void* d_ws, size_t ws_size,
                              hipStream_t stream) {
    const float* q   = (const float*)d_in[0];
    const float* v   = (const float*)d_in[1];
    const float* k_w = (const float*)d_in[2];
    const float* v_w = (const float*)d_in[3];
    const float* qg  = (const float*)d_in[4];
    const float* qb  = (const float*)d_in[5];
    const float* qm  = (const float*)d_in[6];
    const float* qv  = (const float*)d_in[7];
    const float* kg  = (const float*)d_in[8];
    const float* kbe = (const float*)d_in[9];
    const float* km  = (const float*)d_in[10];
    const float* kvv = (const float*)d_in[11];

    unsigned short* Kt = (unsigned short*)d_ws;                    // 1 MB
    unsigned short* Vt = Kt + (size_t)8 * 1024 * 64;               // 1 MB
    float* Opart = (float*)((char*)d_ws + (2u << 20));             // 16 MB (2 splits)
    float* Mpart = Opart + (size_t)2 * 8 * 64 * 4096;              // 256 KB
    float* Lpart = Mpart + (size_t)2 * 8 * 4096;                   // 256 KB

    conv_kv_kernel<<<dim3(64, 8), 256, 0, stream>>>(v, k_w, v_w, kg, kbe, km, kvv, Kt, Vt);
    attn_kernel<<<dim3(64, 8, 2), 256, 0, stream>>>(q, qg, qb, qm, qv, Kt, Vt, Opart, Mpart, Lpart);
    merge_kernel<<<2048, 256, 0, stream>>>(Opart, Mpart, Lpart, (float*)d_out);
}

// Round 9
// 49.678 us; speedup vs baseline: 1.6268x; 1.0290x over previous
//
#include <hip/hip_runtime.h>
#include <hip/hip_bf16.h>

#define EPS 1e-5f

typedef _Float16 f16x8 __attribute__((ext_vector_type(8)));
typedef short short4v __attribute__((ext_vector_type(4)));
typedef short short8v __attribute__((ext_vector_type(8)));
typedef float f32x4 __attribute__((ext_vector_type(4)));

static __device__ __forceinline__ unsigned short f2h(float x) {
    _Float16 h = (_Float16)x;
    return *reinterpret_cast<unsigned short*>(&h);
}

// ------- Kernel 1: 1x1 convs (+BN fold for K): K (B,Nv,64) fp16, V^T (B,64,Nv) fp16 -------
// 8-deep ping-pong prefetch of the (wave-uniform) v float4 -> L2 latency hidden.
__global__ void conv_kv_kernel(const float* __restrict__ v,
                               const float* __restrict__ k_w, const float* __restrict__ v_w,
                               const float* __restrict__ kg, const float* __restrict__ kbe,
                               const float* __restrict__ km, const float* __restrict__ kvv,
                               unsigned short* __restrict__ Kt, unsigned short* __restrict__ Vt) {
    __shared__ float kw_lds[128 * 64];  // [c][o], XOR swizzled
    __shared__ float vw_lds[128 * 64];
    const int t = threadIdx.x;
    const int b = blockIdx.y;
#pragma unroll
    for (int r = 0; r < 32; ++r) {
        int idx = r * 256 + t;
        int o = idx >> 7, c = idx & 127;
        int sw = c * 64 + (o ^ (c & 31));
        kw_lds[sw] = k_w[idx];
        vw_lds[sw] = v_w[idx];
    }
    const int o = t & 63, g = t >> 6;
    const int m0 = blockIdx.x * 16 + g * 4;
    const float invk = kg[o] * rsqrtf(kvv[o] + EPS);
    const float biask = kbe[o] - km[o] * invk;
    __syncthreads();
    float acck[4] = {0.f, 0.f, 0.f, 0.f};
    float accv[4] = {0.f, 0.f, 0.f, 0.f};
    const float* vbase = v + (size_t)b * 128 * 1024 + m0;
    float4 vA[8], vB[8];
#pragma unroll
    for (int j = 0; j < 8; ++j) vA[j] = *reinterpret_cast<const float4*>(vbase + (size_t)j * 1024);
#pragma unroll 1
    for (int cb = 0; cb < 128; cb += 16) {
#pragma unroll
        for (int j = 0; j < 8; ++j)
            vB[j] = *reinterpret_cast<const float4*>(vbase + (size_t)(cb + 8 + j) * 1024);
#pragma unroll
        for (int j = 0; j < 8; ++j) {
            int c = cb + j;
            float kw = kw_lds[c * 64 + (o ^ (c & 31))];
            float vw = vw_lds[c * 64 + (o ^ (c & 31))];
            float4 v0 = vA[j];
            acck[0] += kw * v0.x; acck[1] += kw * v0.y; acck[2] += kw * v0.z; acck[3] += kw * v0.w;
            accv[0] += vw * v0.x; accv[1] += vw * v0.y; accv[2] += vw * v0.z; accv[3] += vw * v0.w;
        }
#pragma unroll
        for (int j = 0; j < 8; ++j)
            vA[j] = *reinterpret_cast<const float4*>(vbase + (size_t)((cb + 16 + j) & 127) * 1024);
#pragma unroll
        for (int j = 0; j < 8; ++j) {
            int c = cb + 8 + j;
            float kw = kw_lds[c * 64 + (o ^ (c & 31))];
            float vw = vw_lds[c * 64 + (o ^ (c & 31))];
            float4 v0 = vB[j];
            acck[0] += kw * v0.x; acck[1] += kw * v0.y; acck[2] += kw * v0.z; acck[3] += kw * v0.w;
            accv[0] += vw * v0.x; accv[1] += vw * v0.y; accv[2] += vw * v0.z; accv[3] += vw * v0.w;
        }
    }
#pragma unroll
    for (int j = 0; j < 4; ++j)
        Kt[(size_t)(b * 1024 + m0 + j) * 64 + o] = f2h(acck[j] * invk + biask);
    unsigned short vb[4];
#pragma unroll
    for (int j = 0; j < 4; ++j) vb[j] = f2h(accv[j]);
    *reinterpret_cast<short4v*>(&Vt[(size_t)(b * 64 + o) * 1024 + m0]) =
        *reinterpret_cast<const short4v*>(vb);
}

// ------- Kernel 2: fused BN(q) + flash attn; 4 waves = 2 q-halves x 2 KV-halves,
//         wave-private LDS tiles, ZERO loop barriers, in-LDS 2-partial merge -------
__global__ __launch_bounds__(256, 3) void attn_kernel(const float* __restrict__ q,
        const float* __restrict__ qg, const float* __restrict__ qbt,
        const float* __restrict__ qm, const float* __restrict__ qv,
        const unsigned short* __restrict__ Kt, const unsigned short* __restrict__ Vt,
        float* __restrict__ out) {
    // LDS map (bytes): [0,38912) 4x(K 32x72 + V 64x40) tiles (epilogue: obuf 4x32x68 f32 overlays)
    //                  [38912,44032) pT 4x(16x40); [44032,44544) ib; [44544,45568) mlbuf
    __shared__ __align__(16) unsigned char smem[45568];
    unsigned short* S16 = (unsigned short*)smem;
    float* SF = (float*)smem;
    const int t = threadIdx.x;
    const int w = t >> 6, lane = t & 63, g = lane >> 4, qr = lane & 15;
    const int p = w & 1, h = w >> 1;                 // q-half, KV-half
    const int b = blockIdx.y, n0 = blockIdx.x * 64;

    unsigned short* kT = S16 + w * 4864;             // [key32][72]
    unsigned short* vT = kT + 2304;                  // [c64][40]
    unsigned short* pT = S16 + 19456 + w * 640;      // [qr16][40]
    float* ib  = SF + 11008;
    float* mlb = SF + 11136;

    const int koff0 = h * 512;
    const int kr_row = lane >> 3, kr_sub = lane & 7; // K staging: 8 rows/chunk, contiguous 1KB/inst
    const int vr_row = lane >> 2, vr_sub = lane & 3; // V staging

    short8v kpf[4], vpf[4];
#pragma unroll
    for (int ch = 0; ch < 4; ++ch) {                 // tile 0 loads in flight under setup
        kpf[ch] = *reinterpret_cast<const short8v*>(
            Kt + (size_t)(b * 1024 + koff0 + ch * 8 + kr_row) * 64 + kr_sub * 8);
        vpf[ch] = *reinterpret_cast<const short8v*>(
            Vt + (size_t)(b * 64 + ch * 16 + vr_row) * 1024 + koff0 + vr_sub * 8);
    }

    if (t < 64) {
        float inv = qg[t] * rsqrtf(qv[t] + EPS);
        ib[t] = inv * 1.44269504f;                   // softmax in base-2
        ib[64 + t] = (qbt[t] - qm[t] * inv) * 1.44269504f;
    }
    __syncthreads();

    const int nqA = n0 + p * 32 + qr, nqB = nqA + 16;
    f16x8 qfA0, qfA1, qfB0, qfB1;
#pragma unroll
    for (int j = 0; j < 8; ++j) {
        int c0 = g * 8 + j, c1 = 32 + g * 8 + j;
        qfA0[j] = (_Float16)(q[(size_t)(b * 64 + c0) * 4096 + nqA] * ib[c0] + ib[64 + c0]);
        qfA1[j] = (_Float16)(q[(size_t)(b * 64 + c1) * 4096 + nqA] * ib[c1] + ib[64 + c1]);
        qfB0[j] = (_Float16)(q[(size_t)(b * 64 + c0) * 4096 + nqB] * ib[c0] + ib[64 + c0]);
        qfB1[j] = (_Float16)(q[(size_t)(b * 64 + c1) * 4096 + nqB] * ib[c1] + ib[64 + c1]);
    }

#pragma unroll
    for (int ch = 0; ch < 4; ++ch) {                 // land tile 0 (wave-private: no barrier)
        *reinterpret_cast<short8v*>(kT + (ch * 8 + kr_row) * 72 + kr_sub * 8) = kpf[ch];
        *reinterpret_cast<short8v*>(vT + (ch * 16 + vr_row) * 40 + vr_sub * 8) = vpf[ch];
    }

    f32x4 oaccA[4], oaccB[4];
#pragma unroll
    for (int cb = 0; cb < 4; ++cb) { oaccA[cb] = (f32x4){0,0,0,0}; oaccB[cb] = (f32x4){0,0,0,0}; }
    float mrA = -1e30f, mrB = -1e30f, lpA = 0.f, lpB = 0.f;

    auto body = [&](const f16x8& q0, const f16x8& q1, f32x4 (&oa)[4], float& mr, float& lp) {
        f32x4 s0, s1;
        {
            f16x8 kf0 = *reinterpret_cast<const f16x8*>(kT + qr * 72 + g * 8);
            f16x8 kf1 = *reinterpret_cast<const f16x8*>(kT + qr * 72 + 32 + g * 8);
            f32x4 a = {0,0,0,0};
            a  = __builtin_amdgcn_mfma_f32_16x16x32_f16(kf0, q0, a, 0, 0, 0);
            s0 = __builtin_amdgcn_mfma_f32_16x16x32_f16(kf1, q1, a, 0, 0, 0);
        }
        {
            f16x8 kf0 = *reinterpret_cast<const f16x8*>(kT + (16 + qr) * 72 + g * 8);
            f16x8 kf1 = *reinterpret_cast<const f16x8*>(kT + (16 + qr) * 72 + 32 + g * 8);
            f32x4 a = {0,0,0,0};
            a  = __builtin_amdgcn_mfma_f32_16x16x32_f16(kf0, q0, a, 0, 0, 0);
            s1 = __builtin_amdgcn_mfma_f32_16x16x32_f16(kf1, q1, a, 0, 0, 0);
        }
        float lmax = fmaxf(fmaxf(fmaxf(s0[0], s0[1]), fmaxf(s0[2], s0[3])),
                           fmaxf(fmaxf(s1[0], s1[1]), fmaxf(s1[2], s1[3])));
        if (!__all(lmax - mr <= 11.0f)) {
            float tm = fmaxf(lmax, __shfl_xor(lmax, 16));
            tm = fmaxf(tm, __shfl_xor(tm, 32));
            float mn = fmaxf(mr, tm);
            float sc = exp2f(mr - mn);
            lp *= sc;
            oa[0] *= sc; oa[1] *= sc; oa[2] *= sc; oa[3] *= sc;
            mr = mn;
        }
        float p0 = exp2f(s0[0] - mr), p1 = exp2f(s0[1] - mr);
        float p2 = exp2f(s0[2] - mr), p3 = exp2f(s0[3] - mr);
        float p4 = exp2f(s1[0] - mr), p5 = exp2f(s1[1] - mr);
        float p6 = exp2f(s1[2] - mr), p7 = exp2f(s1[3] - mr);
        lp += ((p0 + p1) + (p2 + p3)) + ((p4 + p5) + (p6 + p7));
        uint2 w0, w1;
        w0.x = __builtin_bit_cast(unsigned int, __builtin_amdgcn_cvt_pkrtz(p0, p1));
        w0.y = __builtin_bit_cast(unsigned int, __builtin_amdgcn_cvt_pkrtz(p2, p3));
        w1.x = __builtin_bit_cast(unsigned int, __builtin_amdgcn_cvt_pkrtz(p4, p5));
        w1.y = __builtin_bit_cast(unsigned int, __builtin_amdgcn_cvt_pkrtz(p6, p7));
        *reinterpret_cast<uint2*>(pT + qr * 40 + g * 4) = w0;        // keys 4g..4g+3
        *reinterpret_cast<uint2*>(pT + qr * 40 + 16 + g * 4) = w1;   // keys 16+4g..
        f16x8 pf = *reinterpret_cast<const f16x8*>(pT + qr * 40 + g * 8);
#pragma unroll
        for (int cb = 0; cb < 4; ++cb) {
            f16x8 vf = *reinterpret_cast<const f16x8*>(vT + (cb * 16 + qr) * 40 + g * 8);
            oa[cb] = __builtin_amdgcn_mfma_f32_16x16x32_f16(vf, pf, oa[cb], 0, 0, 0);
        }
    };

#pragma unroll 1
    for (int i = 0; i < 16; ++i) {
        if (i < 15) {                                // T14: next tile loads issued first
            int ko = koff0 + (i + 1) * 32;
#pragma unroll
            for (int ch = 0; ch < 4; ++ch) {
                kpf[ch] = *reinterpret_cast<const short8v*>(
                    Kt + (size_t)(b * 1024 + ko + ch * 8 + kr_row) * 64 + kr_sub * 8);
                vpf[ch] = *reinterpret_cast<const short8v*>(
                    Vt + (size_t)(b * 64 + ch * 16 + vr_row) * 1024 + ko + vr_sub * 8);
            }
        }
        body(qfA0, qfA1, oaccA, mrA, lpA);
        body(qfB0, qfB1, oaccB, mrB, lpB);
        if (i < 15) {                                // wave-private overwrite (lgkmcnt only)
#pragma unroll
            for (int ch = 0; ch < 4; ++ch) {
                *reinterpret_cast<short8v*>(kT + (ch * 8 + kr_row) * 72 + kr_sub * 8) = kpf[ch];
                *reinterpret_cast<short8v*>(vT + (ch * 16 + vr_row) * 40 + vr_sub * 8) = vpf[ch];
            }
        }
    }

    float lA = lpA + __shfl_xor(lpA, 16); lA += __shfl_xor(lA, 32);
    float lB = lpB + __shfl_xor(lpB, 16); lB += __shfl_xor(lB, 32);
    __syncthreads();                                 // tiles dead; obuf overlays them
    float* ob = SF + w * 2176;                       // [row32][68] f32
#pragma unroll
    for (int cb = 0; cb < 4; ++cb) {
        *reinterpret_cast<f32x4*>(&ob[qr * 68 + cb * 16 + g * 4]) = oaccA[cb];
        *reinterpret_cast<f32x4*>(&ob[(16 + qr) * 68 + cb * 16 + g * 4]) = oaccB[cb];
    }
    if (g == 0) {
        mlb[w * 64 + qr * 2] = mrA;        mlb[w * 64 + qr * 2 + 1] = lA;
        mlb[w * 64 + (16 + qr) * 2] = mrB; mlb[w * 64 + (16 + qr) * 2 + 1] = lB;
    }
    __syncthreads();
    // merge: wave w -> q-half p2 = w&1, row-block hh = w>>1; partials = waves p2 (h=0), 2+p2 (h=1)
    const int p2 = w & 1, hh = w >> 1;
    const int rowrel = hh * 16 + qr;
    const float* o0 = SF + p2 * 2176 + rowrel * 68;
    const float* o1 = SF + (2 + p2) * 2176 + rowrel * 68;
    float m0 = mlb[p2 * 64 + rowrel * 2],       l0 = mlb[p2 * 64 + rowrel * 2 + 1];
    float m1 = mlb[(2 + p2) * 64 + rowrel * 2], l1 = mlb[(2 + p2) * 64 + rowrel * 2 + 1];
    float M = fmaxf(m0, m1);
    float w0 = exp2f(m0 - M), w1 = exp2f(m1 - M);
    float rd = 1.0f / (w0 * l0 + w1 * l1);
    const int nout = n0 + p2 * 32 + rowrel;
#pragma unroll
    for (int j = 0; j < 16; ++j) {
        int c = j * 4 + g;
        out[(size_t)(b * 64 + c) * 4096 + nout] = (o0[c] * w0 + o1[c] * w1) * rd;
    }
}

extern "C" void kernel_launch(void* const* d_in, const int* in_sizes, int n_in,
                              void* d_out, int out_size, void* d_ws, size_t ws_size,
                              hipStream_t stream) {
    const float* q   = (const float*)d_in[0];
    const float* v   = (const float*)d_in[1];
    const float* k_w = (const float*)d_in[2];
    const float* v_w = (const float*)d_in[3];
    const float* qg  = (const float*)d_in[4];
    const float* qb  = (const float*)d_in[5];
    const float* qm  = (const float*)d_in[6];
    const float* qv  = (const float*)d_in[7];
    const float* kg  = (const float*)d_in[8];
    const float* kbe = (const float*)d_in[9];
    const float* km  = (const float*)d_in[10];
    const float* kvv = (const float*)d_in[11];

    unsigned short* Kt = (unsigned short*)d_ws;            // 8*1024*64 fp16 = 1 MB
    unsigned short* Vt = Kt + (size_t)8 * 1024 * 64;       // 1 MB

    conv_kv_kernel<<<dim3(64, 8), 256, 0, stream>>>(v, k_w, v_w, kg, kbe, km, kvv, Kt, Vt);
    attn_kernel<<<dim3(64, 8), 256, 0, stream>>>(q, qg, qb, qm, qv, Kt, Vt, (float*)d_out);
}

// Round 10
// 39.169 us; speedup vs baseline: 2.0632x; 1.2683x over previous
//
#include <hip/hip_runtime.h>
#include <hip/hip_bf16.h>

#define EPS 1e-5f

typedef _Float16 f16x8 __attribute__((ext_vector_type(8)));
typedef short short8v __attribute__((ext_vector_type(8)));
typedef float f32x4 __attribute__((ext_vector_type(4)));

static __device__ __forceinline__ unsigned short f2h(float x) {
    _Float16 h = (_Float16)x;
    return *reinterpret_cast<unsigned short*>(&h);
}

// ------- Kernel 1: 1x1 convs as MFMA GEMM: K (B,Nv,64) fp16, V^T (B,64,Nv) fp16 -------
// grid (32, 8): WG = 32-m tile, 4 waves = 4 o-blocks of 16. 16 MFMA/wave, K-dim 128.
__global__ __launch_bounds__(256) void conv_kv_kernel(const float* __restrict__ v,
                               const float* __restrict__ k_w, const float* __restrict__ v_w,
                               const float* __restrict__ kg, const float* __restrict__ kbe,
                               const float* __restrict__ km, const float* __restrict__ kvv,
                               unsigned short* __restrict__ Kt, unsigned short* __restrict__ Vt) {
    __shared__ unsigned short vtile[32 * 136];       // [m][c] fp16, stride 136 (272B, 16B-mult)
    const int t = threadIdx.x;
    const int w = t >> 6, lane = t & 63, g = lane >> 4, qr = lane & 15;
    const int b = blockIdx.y, m0 = blockIdx.x * 32;

    // stage v-tile: 128c x 32m floats; coalesced float4 reads (8 threads = 128B run per c)
    float4 vstg[4];
#pragma unroll
    for (int r = 0; r < 4; ++r) {
        int idx = r * 256 + t;                       // 0..1023
        int c = idx >> 3, mq = idx & 7;
        vstg[r] = *reinterpret_cast<const float4*>(&v[((size_t)b * 128 + c) * 1024 + m0 + mq * 4]);
    }
    // weight A-frags in flight: row o=16w+qr, k-chunk ck: c=32ck+8g+j
    float4 kwl[4][2], vwl[4][2];
#pragma unroll
    for (int ck = 0; ck < 4; ++ck) {
        const float* kp = &k_w[(16 * w + qr) * 128 + 32 * ck + 8 * g];
        const float* vp = &v_w[(16 * w + qr) * 128 + 32 * ck + 8 * g];
        kwl[ck][0] = *reinterpret_cast<const float4*>(kp);
        kwl[ck][1] = *reinterpret_cast<const float4*>(kp + 4);
        vwl[ck][0] = *reinterpret_cast<const float4*>(vp);
        vwl[ck][1] = *reinterpret_cast<const float4*>(vp + 4);
    }
    // transpose-write v tile to LDS as fp16
#pragma unroll
    for (int r = 0; r < 4; ++r) {
        int idx = r * 256 + t;
        int c = idx >> 3, mq = idx & 7;
        vtile[(mq * 4 + 0) * 136 + c] = f2h(vstg[r].x);
        vtile[(mq * 4 + 1) * 136 + c] = f2h(vstg[r].y);
        vtile[(mq * 4 + 2) * 136 + c] = f2h(vstg[r].z);
        vtile[(mq * 4 + 3) * 136 + c] = f2h(vstg[r].w);
    }
    __syncthreads();

    f16x8 kwf[4], vwf[4];
#pragma unroll
    for (int ck = 0; ck < 4; ++ck)
#pragma unroll
        for (int j = 0; j < 8; ++j) {
            kwf[ck][j] = (_Float16)(j < 4 ? kwl[ck][0][j] : kwl[ck][1][j - 4]);
            vwf[ck][j] = (_Float16)(j < 4 ? vwl[ck][0][j] : vwl[ck][1][j - 4]);
        }

    // per mb (16 m's): B-frags from LDS, 8 MFMA (K and V share the B-frags)
    f32x4 accK[2], accV[2];
#pragma unroll
    for (int mb = 0; mb < 2; ++mb) {
        f16x8 bf[4];
#pragma unroll
        for (int ck = 0; ck < 4; ++ck)
            bf[ck] = *reinterpret_cast<const f16x8*>(&vtile[(mb * 16 + qr) * 136 + 32 * ck + 8 * g]);
        f32x4 aK = {0.f, 0.f, 0.f, 0.f}, aV = {0.f, 0.f, 0.f, 0.f};
#pragma unroll
        for (int ck = 0; ck < 4; ++ck) {
            aK = __builtin_amdgcn_mfma_f32_16x16x32_f16(kwf[ck], bf[ck], aK, 0, 0, 0);
            aV = __builtin_amdgcn_mfma_f32_16x16x32_f16(vwf[ck], bf[ck], aV, 0, 0, 0);
        }
        accK[mb] = aK; accV[mb] = aV;
    }

    // epilogue: D row = o_sub = 4g+i, col = m_sub = qr; BN fold on K
    float invk_i[4], biask_i[4];
#pragma unroll
    for (int i = 0; i < 4; ++i) {
        int o = 16 * w + 4 * g + i;
        invk_i[i] = kg[o] * rsqrtf(kvv[o] + EPS);
        biask_i[i] = kbe[o] - km[o] * invk_i[i];
    }
#pragma unroll
    for (int mb = 0; mb < 2; ++mb) {
        int m = m0 + mb * 16 + qr;
#pragma unroll
        for (int i = 0; i < 4; ++i) {
            int o = 16 * w + 4 * g + i;
            Kt[((size_t)b * 1024 + m) * 64 + o] = f2h(accK[mb][i] * invk_i[i] + biask_i[i]);
            Vt[((size_t)b * 64 + o) * 1024 + m] = f2h(accV[mb][i]);
        }
    }
}

// ------- Kernel 2: fused BN(q) + flash attn; 4 waves = 2 q-halves x 2 KV-halves,
//         wave-private LDS tiles, ZERO loop barriers, in-LDS 2-partial merge -------
__global__ __launch_bounds__(256, 2) void attn_kernel(const float* __restrict__ q,
        const float* __restrict__ qg, const float* __restrict__ qbt,
        const float* __restrict__ qm, const float* __restrict__ qv,
        const unsigned short* __restrict__ Kt, const unsigned short* __restrict__ Vt,
        float* __restrict__ out) {
    // LDS map (bytes): [0,38912) 4x(K 32x72 + V 64x40) tiles (epilogue: obuf 4x32x68 f32 overlays)
    //                  [38912,44032) pT 4x(16x40); [44032,44544) ib; [44544,45568) mlbuf
    __shared__ __align__(16) unsigned char smem[45568];
    unsigned short* S16 = (unsigned short*)smem;
    float* SF = (float*)smem;
    const int t = threadIdx.x;
    const int w = t >> 6, lane = t & 63, g = lane >> 4, qr = lane & 15;
    const int p = w & 1, h = w >> 1;                 // q-half, KV-half
    const int b = blockIdx.y, n0 = blockIdx.x * 64;

    unsigned short* kT = S16 + w * 4864;             // [key32][72]
    unsigned short* vT = kT + 2304;                  // [c64][40]
    unsigned short* pT = S16 + 19456 + w * 640;      // [qr16][40]
    float* ib  = SF + 11008;
    float* mlb = SF + 11136;

    const int koff0 = h * 512;
    const int kr_row = lane >> 3, kr_sub = lane & 7; // K staging: 8 rows/chunk, contiguous 1KB/inst
    const int vr_row = lane >> 2, vr_sub = lane & 3; // V staging

    short8v kpf[4], vpf[4];
#pragma unroll
    for (int ch = 0; ch < 4; ++ch) {                 // tile 0 loads in flight under setup
        kpf[ch] = *reinterpret_cast<const short8v*>(
            Kt + (size_t)(b * 1024 + koff0 + ch * 8 + kr_row) * 64 + kr_sub * 8);
        vpf[ch] = *reinterpret_cast<const short8v*>(
            Vt + (size_t)(b * 64 + ch * 16 + vr_row) * 1024 + koff0 + vr_sub * 8);
    }

    if (t < 64) {
        float inv = qg[t] * rsqrtf(qv[t] + EPS);
        ib[t] = inv * 1.44269504f;                   // softmax in base-2
        ib[64 + t] = (qbt[t] - qm[t] * inv) * 1.44269504f;
    }
    __syncthreads();

    const int nqA = n0 + p * 32 + qr, nqB = nqA + 16;
    f16x8 qfA0, qfA1, qfB0, qfB1;
#pragma unroll
    for (int j = 0; j < 8; ++j) {
        int c0 = g * 8 + j, c1 = 32 + g * 8 + j;
        qfA0[j] = (_Float16)(q[(size_t)(b * 64 + c0) * 4096 + nqA] * ib[c0] + ib[64 + c0]);
        qfA1[j] = (_Float16)(q[(size_t)(b * 64 + c1) * 4096 + nqA] * ib[c1] + ib[64 + c1]);
        qfB0[j] = (_Float16)(q[(size_t)(b * 64 + c0) * 4096 + nqB] * ib[c0] + ib[64 + c0]);
        qfB1[j] = (_Float16)(q[(size_t)(b * 64 + c1) * 4096 + nqB] * ib[c1] + ib[64 + c1]);
    }

#pragma unroll
    for (int ch = 0; ch < 4; ++ch) {                 // land tile 0 (wave-private: no barrier)
        *reinterpret_cast<short8v*>(kT + (ch * 8 + kr_row) * 72 + kr_sub * 8) = kpf[ch];
        *reinterpret_cast<short8v*>(vT + (ch * 16 + vr_row) * 40 + vr_sub * 8) = vpf[ch];
    }

    f32x4 oaccA[4], oaccB[4];
#pragma unroll
    for (int cb = 0; cb < 4; ++cb) { oaccA[cb] = (f32x4){0,0,0,0}; oaccB[cb] = (f32x4){0,0,0,0}; }
    float mrA = -1e30f, mrB = -1e30f, lpA = 0.f, lpB = 0.f;

    auto body = [&](const f16x8& q0, const f16x8& q1, f32x4 (&oa)[4], float& mr, float& lp) {
        f32x4 s0, s1;
        {
            f16x8 kf0 = *reinterpret_cast<const f16x8*>(kT + qr * 72 + g * 8);
            f16x8 kf1 = *reinterpret_cast<const f16x8*>(kT + qr * 72 + 32 + g * 8);
            f32x4 a = {0,0,0,0};
            a  = __builtin_amdgcn_mfma_f32_16x16x32_f16(kf0, q0, a, 0, 0, 0);
            s0 = __builtin_amdgcn_mfma_f32_16x16x32_f16(kf1, q1, a, 0, 0, 0);
        }
        {
            f16x8 kf0 = *reinterpret_cast<const f16x8*>(kT + (16 + qr) * 72 + g * 8);
            f16x8 kf1 = *reinterpret_cast<const f16x8*>(kT + (16 + qr) * 72 + 32 + g * 8);
            f32x4 a = {0,0,0,0};
            a  = __builtin_amdgcn_mfma_f32_16x16x32_f16(kf0, q0, a, 0, 0, 0);
            s1 = __builtin_amdgcn_mfma_f32_16x16x32_f16(kf1, q1, a, 0, 0, 0);
        }
        float lmax = fmaxf(fmaxf(fmaxf(s0[0], s0[1]), fmaxf(s0[2], s0[3])),
                           fmaxf(fmaxf(s1[0], s1[1]), fmaxf(s1[2], s1[3])));
        if (!__all(lmax - mr <= 11.0f)) {
            float tm = fmaxf(lmax, __shfl_xor(lmax, 16));
            tm = fmaxf(tm, __shfl_xor(tm, 32));
            float mn = fmaxf(mr, tm);
            float sc = exp2f(mr - mn);
            lp *= sc;
            oa[0] *= sc; oa[1] *= sc; oa[2] *= sc; oa[3] *= sc;
            mr = mn;
        }
        float p0 = exp2f(s0[0] - mr), p1 = exp2f(s0[1] - mr);
        float p2 = exp2f(s0[2] - mr), p3 = exp2f(s0[3] - mr);
        float p4 = exp2f(s1[0] - mr), p5 = exp2f(s1[1] - mr);
        float p6 = exp2f(s1[2] - mr), p7 = exp2f(s1[3] - mr);
        lp += ((p0 + p1) + (p2 + p3)) + ((p4 + p5) + (p6 + p7));
        uint2 w0, w1;
        w0.x = __builtin_bit_cast(unsigned int, __builtin_amdgcn_cvt_pkrtz(p0, p1));
        w0.y = __builtin_bit_cast(unsigned int, __builtin_amdgcn_cvt_pkrtz(p2, p3));
        w1.x = __builtin_bit_cast(unsigned int, __builtin_amdgcn_cvt_pkrtz(p4, p5));
        w1.y = __builtin_bit_cast(unsigned int, __builtin_amdgcn_cvt_pkrtz(p6, p7));
        *reinterpret_cast<uint2*>(pT + qr * 40 + g * 4) = w0;        // keys 4g..4g+3
        *reinterpret_cast<uint2*>(pT + qr * 40 + 16 + g * 4) = w1;   // keys 16+4g..
        f16x8 pf = *reinterpret_cast<const f16x8*>(pT + qr * 40 + g * 8);
#pragma unroll
        for (int cb = 0; cb < 4; ++cb) {
            f16x8 vf = *reinterpret_cast<const f16x8*>(vT + (cb * 16 + qr) * 40 + g * 8);
            oa[cb] = __builtin_amdgcn_mfma_f32_16x16x32_f16(vf, pf, oa[cb], 0, 0, 0);
        }
    };

#pragma unroll 1
    for (int i = 0; i < 16; ++i) {
        if (i < 15) {                                // T14: next tile loads issued first
            int ko = koff0 + (i + 1) * 32;
#pragma unroll
            for (int ch = 0; ch < 4; ++ch) {
                kpf[ch] = *reinterpret_cast<const short8v*>(
                    Kt + (size_t)(b * 1024 + ko + ch * 8 + kr_row) * 64 + kr_sub * 8);
                vpf[ch] = *reinterpret_cast<const short8v*>(
                    Vt + (size_t)(b * 64 + ch * 16 + vr_row) * 1024 + ko + vr_sub * 8);
            }
        }
        body(qfA0, qfA1, oaccA, mrA, lpA);
        body(qfB0, qfB1, oaccB, mrB, lpB);
        if (i < 15) {                                // wave-private overwrite (lgkmcnt only)
#pragma unroll
            for (int ch = 0; ch < 4; ++ch) {
                *reinterpret_cast<short8v*>(kT + (ch * 8 + kr_row) * 72 + kr_sub * 8) = kpf[ch];
                *reinterpret_cast<short8v*>(vT + (ch * 16 + vr_row) * 40 + vr_sub * 8) = vpf[ch];
            }
        }
    }

    float lA = lpA + __shfl_xor(lpA, 16); lA += __shfl_xor(lA, 32);
    float lB = lpB + __shfl_xor(lpB, 16); lB += __shfl_xor(lB, 32);
    __syncthreads();                                 // tiles dead; obuf overlays them
    float* ob = SF + w * 2176;                       // [row32][68] f32
#pragma unroll
    for (int cb = 0; cb < 4; ++cb) {
        *reinterpret_cast<f32x4*>(&ob[qr * 68 + cb * 16 + g * 4]) = oaccA[cb];
        *reinterpret_cast<f32x4*>(&ob[(16 + qr) * 68 + cb * 16 + g * 4]) = oaccB[cb];
    }
    if (g == 0) {
        mlb[w * 64 + qr * 2] = mrA;        mlb[w * 64 + qr * 2 + 1] = lA;
        mlb[w * 64 + (16 + qr) * 2] = mrB; mlb[w * 64 + (16 + qr) * 2 + 1] = lB;
    }
    __syncthreads();
    // merge: wave w -> q-half p2 = w&1, row-block hh = w>>1; partials = waves p2 (h=0), 2+p2 (h=1)
    const int p2 = w & 1, hh = w >> 1;
    const int rowrel = hh * 16 + qr;
    const float* o0 = SF + p2 * 2176 + rowrel * 68;
    const float* o1 = SF + (2 + p2) * 2176 + rowrel * 68;
    float m0 = mlb[p2 * 64 + rowrel * 2],       l0 = mlb[p2 * 64 + rowrel * 2 + 1];
    float m1 = mlb[(2 + p2) * 64 + rowrel * 2], l1 = mlb[(2 + p2) * 64 + rowrel * 2 + 1];
    float M = fmaxf(m0, m1);
    float w0 = exp2f(m0 - M), w1 = exp2f(m1 - M);
    float rd = 1.0f / (w0 * l0 + w1 * l1);
    const int nout = n0 + p2 * 32 + rowrel;
#pragma unroll
    for (int j = 0; j < 16; ++j) {
        int c = j * 4 + g;
        out[(size_t)(b * 64 + c) * 4096 + nout] = (o0[c] * w0 + o1[c] * w1) * rd;
    }
}

extern "C" void kernel_launch(void* const* d_in, const int* in_sizes, int n_in,
                              void* d_out, int out_size, void* d_ws, size_t ws_size,
                              hipStream_t stream) {
    const float* q   = (const float*)d_in[0];
    const float* v   = (const float*)d_in[1];
    const float* k_w = (const float*)d_in[2];
    const float* v_w = (const float*)d_in[3];
    const float* qg  = (const float*)d_in[4];
    const float* qb  = (const float*)d_in[5];
    const float* qm  = (const float*)d_in[6];
    const float* qv  = (const float*)d_in[7];
    const float* kg  = (const float*)d_in[8];
    const float* kbe = (const float*)d_in[9];
    const float* km  = (const float*)d_in[10];
    const float* kvv = (const float*)d_in[11];

    unsigned short* Kt = (unsigned short*)d_ws;            // 8*1024*64 fp16 = 1 MB
    unsigned short* Vt = Kt + (size_t)8 * 1024 * 64;       // 1 MB

    conv_kv_kernel<<<dim3(32, 8), 256, 0, stream>>>(v, k_w, v_w, kg, kbe, km, kvv, Kt, Vt);
    attn_kernel<<<dim3(64, 8), 256, 0, stream>>>(q, qg, qb, qm, qv, Kt, Vt, (float*)d_out);
}